// Round 1
// baseline (278.669 us; speedup 1.0000x reference)
//
#include <hip/hip_runtime.h>

// Problem constants (fixed by the reference):
#define N_ROWS 262144
#define DIM    128
#define HID    16
#define NEXP   21
// Segments of 64 rows, each expert's region padded up to a multiple of 64.
#define NSEG   (N_ROWS / 64 + NEXP)   // 4096 + 21 = 4117 worst case
#define NBLK1  256                    // blocks for hist/scatter
#define RPB    (N_ROWS / NBLK1)       // 1024 rows per block
#define RPT    (RPB / 256)            // 4 rows per thread

// ---------------------------------------------------------------------------
// K1: per-block histogram of sid + reserve a per-(block,expert) range in the
// global per-expert row lists via one atomicAdd per (block,expert).
// ---------------------------------------------------------------------------
__global__ __launch_bounds__(256) void k_hist(const int* __restrict__ sid,
                                              int* __restrict__ counts,
                                              int* __restrict__ blockBase) {
    __shared__ int lh[NEXP];
    int t = threadIdx.x;
    if (t < NEXP) lh[t] = 0;
    __syncthreads();
    int base = blockIdx.x * RPB + t;
#pragma unroll
    for (int r = 0; r < RPT; r++) {
        atomicAdd(&lh[sid[base + r * 256]], 1);
    }
    __syncthreads();
    if (t < NEXP) blockBase[blockIdx.x * NEXP + t] = atomicAdd(&counts[t], lh[t]);
}

// ---------------------------------------------------------------------------
// K2: each block recomputes the padded exclusive scan of the (now final)
// expert counts, then scatters its rows into bucket[paddedBase[e] +
// blockBase[b][e] + localPos].  Unfilled tail slots stay -1 (memset 0xFF).
// ---------------------------------------------------------------------------
__global__ __launch_bounds__(256) void k_scatter(const int* __restrict__ sid,
                                                 const int* __restrict__ counts,
                                                 const int* __restrict__ blockBase,
                                                 int* __restrict__ buckets) {
    __shared__ int sbase[NEXP];
    __shared__ int lcur[NEXP];
    int t = threadIdx.x;
    if (t == 0) {
        int acc = 0;
        for (int e = 0; e < NEXP; e++) {
            sbase[e] = acc + blockBase[blockIdx.x * NEXP + e];
            acc += ((counts[e] + 63) >> 6) << 6;   // pad each expert to 64
        }
    }
    if (t < NEXP) lcur[t] = 0;
    __syncthreads();
    int base = blockIdx.x * RPB + t;
#pragma unroll
    for (int r = 0; r < RPT; r++) {
        int row = base + r * 256;
        int e = sid[row];
        int lp = atomicAdd(&lcur[e], 1);
        buckets[sbase[e] + lp] = row;
    }
}

// ---------------------------------------------------------------------------
// K3: one wave (64 lanes) per segment; all valid rows in a segment share one
// expert, so e is wave-uniform (readfirstlane) and all weight accesses are
// scalar loads.  Each lane computes one full row: 2048 v_fmac_f32 with SGPR
// W1 operands, x streamed as float4 from global (512 B/row, dense lines).
// ---------------------------------------------------------------------------
__global__ __launch_bounds__(256) void k_main(const float* __restrict__ x,
                                              const int* __restrict__ sid,
                                              const float* __restrict__ W1,
                                              const float* __restrict__ b1,
                                              const float* __restrict__ W2,
                                              const float* __restrict__ b2,
                                              const int* __restrict__ buckets,
                                              float* __restrict__ out) {
    int seg = blockIdx.x * 4 + (threadIdx.x >> 6);
    if (seg >= NSEG) return;
    int lane = threadIdx.x & 63;
    int row = buckets[seg * 64 + lane];
    unsigned long long bal = __ballot(row >= 0);
    if (bal == 0ULL) return;                 // wholly-empty tail segment
    // Valid slots form a prefix of the segment -> lane 0 is valid.
    int vrow = (row >= 0) ? row : 0;         // invalid lanes do harmless work
    int e = __builtin_amdgcn_readfirstlane(sid[vrow]);  // wave-uniform expert

    const float* __restrict__ w1 = W1 + e * (DIM * HID);
    const float* __restrict__ xr = x + (size_t)vrow * DIM;

    float h[HID];
#pragma unroll
    for (int j = 0; j < HID; j++) h[j] = b1[e * HID + j];

    float4 cur = *(const float4*)(xr);
#pragma unroll 2
    for (int c = 0; c < DIM / 4; c++) {
        float4 nxt = (c < DIM / 4 - 1) ? *(const float4*)(xr + (c + 1) * 4) : cur;
        const float xk0 = cur.x, xk1 = cur.y, xk2 = cur.z, xk3 = cur.w;
        int k = c * 4;
#pragma unroll
        for (int j = 0; j < HID; j++) h[j] = fmaf(xk0, w1[(k + 0) * HID + j], h[j]);
#pragma unroll
        for (int j = 0; j < HID; j++) h[j] = fmaf(xk1, w1[(k + 1) * HID + j], h[j]);
#pragma unroll
        for (int j = 0; j < HID; j++) h[j] = fmaf(xk2, w1[(k + 2) * HID + j], h[j]);
#pragma unroll
        for (int j = 0; j < HID; j++) h[j] = fmaf(xk3, w1[(k + 3) * HID + j], h[j]);
        cur = nxt;
    }

    float acc = b2[e];
#pragma unroll
    for (int j = 0; j < HID; j++) acc = fmaf(fmaxf(h[j], 0.0f), W2[e * HID + j], acc);
    float y = fmaxf(acc, 0.0f);
    if (row >= 0) out[row] = y;
}

// ---------------------------------------------------------------------------
// Fallback (only if ws_size is too small for the buckets): thread-per-row,
// per-lane W1 gather from L2.  Correct but slow.
// ---------------------------------------------------------------------------
__global__ __launch_bounds__(256) void k_naive(const float* __restrict__ x,
                                               const int* __restrict__ sid,
                                               const float* __restrict__ W1,
                                               const float* __restrict__ b1,
                                               const float* __restrict__ W2,
                                               const float* __restrict__ b2,
                                               float* __restrict__ out) {
    int row = blockIdx.x * 256 + threadIdx.x;
    if (row >= N_ROWS) return;
    int e = sid[row];
    const float* w1 = W1 + e * (DIM * HID);
    const float* xr = x + (size_t)row * DIM;
    float h[HID];
#pragma unroll
    for (int j = 0; j < HID; j++) h[j] = b1[e * HID + j];
    for (int k = 0; k < DIM; k++) {
        float xk = xr[k];
#pragma unroll
        for (int j = 0; j < HID; j++) h[j] = fmaf(xk, w1[k * HID + j], h[j]);
    }
    float acc = b2[e];
#pragma unroll
    for (int j = 0; j < HID; j++) acc = fmaf(fmaxf(h[j], 0.0f), W2[e * HID + j], acc);
    out[row] = fmaxf(acc, 0.0f);
}

extern "C" void kernel_launch(void* const* d_in, const int* in_sizes, int n_in,
                              void* d_out, int out_size, void* d_ws, size_t ws_size,
                              hipStream_t stream) {
    const float* x   = (const float*)d_in[0];
    const int*   sid = (const int*)d_in[1];
    const float* W1  = (const float*)d_in[2];
    const float* b1  = (const float*)d_in[3];
    const float* W2  = (const float*)d_in[4];
    const float* b2  = (const float*)d_in[5];
    float* out = (float*)d_out;

    // Workspace layout: buckets | counts(32) | blockBase(NBLK1*NEXP)
    const size_t bucketBytes = (size_t)NSEG * 64 * sizeof(int);
    const size_t countBytes  = 32 * sizeof(int);
    const size_t bbBytes     = (size_t)NBLK1 * NEXP * sizeof(int);
    const size_t need = bucketBytes + countBytes + bbBytes;

    if (ws_size < need) {
        // Safety net: correct but unoptimized.
        k_naive<<<(N_ROWS + 255) / 256, 256, 0, stream>>>(x, sid, W1, b1, W2, b2, out);
        return;
    }

    char* ws = (char*)d_ws;
    int* buckets   = (int*)ws;
    int* counts    = (int*)(ws + bucketBytes);
    int* blockBase = (int*)(ws + bucketBytes + countBytes);

    hipMemsetAsync(buckets, 0xFF, bucketBytes, stream);   // all -1
    hipMemsetAsync(counts, 0, countBytes, stream);
    k_hist<<<NBLK1, 256, 0, stream>>>(sid, counts, blockBase);
    k_scatter<<<NBLK1, 256, 0, stream>>>(sid, counts, blockBase, buckets);
    k_main<<<(NSEG + 3) / 4, 256, 0, stream>>>(x, sid, W1, b1, W2, b2, buckets, out);
}

// Round 2
// 236.091 us; speedup vs baseline: 1.1803x; 1.1803x over previous
//
#include <hip/hip_runtime.h>

// Problem constants (fixed by the reference):
#define N_ROWS 262144
#define DIM    128
#define HID    16
#define NEXP   21
// Segments of 64 rows, each expert's region padded up to a multiple of 64.
#define NSEG   (N_ROWS / 64 + NEXP)   // 4096 + 21 = 4117 worst case
#define NBLK1  256                    // blocks for hist/scatter
#define RPB    (N_ROWS / NBLK1)       // 1024 rows per block
#define RPT    (RPB / 256)            // 4 rows per thread

// ---------------------------------------------------------------------------
// K1: per-block histogram of sid + reserve a per-(block,expert) range in the
// global per-expert row lists via one atomicAdd per (block,expert).
// ---------------------------------------------------------------------------
__global__ __launch_bounds__(256) void k_hist(const int* __restrict__ sid,
                                              int* __restrict__ counts,
                                              int* __restrict__ blockBase) {
    __shared__ int lh[NEXP];
    int t = threadIdx.x;
    if (t < NEXP) lh[t] = 0;
    __syncthreads();
    int base = blockIdx.x * RPB + t;
#pragma unroll
    for (int r = 0; r < RPT; r++) {
        atomicAdd(&lh[sid[base + r * 256]], 1);
    }
    __syncthreads();
    if (t < NEXP) blockBase[blockIdx.x * NEXP + t] = atomicAdd(&counts[t], lh[t]);
}

// ---------------------------------------------------------------------------
// K2: scatter rows into per-expert 64-padded buckets.  Entry = row | (e<<24)
// so k_main never touches sid (drops a scattered gather).  Tail slots = -1.
// ---------------------------------------------------------------------------
__global__ __launch_bounds__(256) void k_scatter(const int* __restrict__ sid,
                                                 const int* __restrict__ counts,
                                                 const int* __restrict__ blockBase,
                                                 int* __restrict__ buckets) {
    __shared__ int sbase[NEXP];
    __shared__ int lcur[NEXP];
    int t = threadIdx.x;
    if (t == 0) {
        int acc = 0;
        for (int e = 0; e < NEXP; e++) {
            sbase[e] = acc + blockBase[blockIdx.x * NEXP + e];
            acc += ((counts[e] + 63) >> 6) << 6;   // pad each expert to 64
        }
    }
    if (t < NEXP) lcur[t] = 0;
    __syncthreads();
    int base = blockIdx.x * RPB + t;
#pragma unroll
    for (int r = 0; r < RPT; r++) {
        int row = base + r * 256;
        int e = sid[row];
        int lp = atomicAdd(&lcur[e], 1);
        buckets[sbase[e] + lp] = row | (e << 24);
    }
}

// ---------------------------------------------------------------------------
// K3: one wave per 64-row same-expert segment; expert is wave-uniform so all
// W1/b1/W2/b2 accesses are scalar (SGPR) loads.  Explicit 4-deep double-
// buffered float4 pipeline keeps 4 scattered vector loads in flight per wave
// (round-1 compiler collapsed the pipeline to depth ~1 -> 1.95 TB/s).
// __launch_bounds__(256,4): grid caps occupancy at 16 waves/CU anyway, so
// allow up to ~128 VGPRs -> no h[16] spill.
// ---------------------------------------------------------------------------
__global__ __launch_bounds__(256, 4) void k_main(const float* __restrict__ x,
                                                 const float* __restrict__ W1,
                                                 const float* __restrict__ b1,
                                                 const float* __restrict__ W2,
                                                 const float* __restrict__ b2,
                                                 const int* __restrict__ buckets,
                                                 float* __restrict__ out) {
    int seg = blockIdx.x * 4 + (threadIdx.x >> 6);
    if (seg >= NSEG) return;
    int lane = threadIdx.x & 63;
    int ent = buckets[seg * 64 + lane];
    if (__ballot(ent >= 0) == 0ULL) return;       // wholly-empty tail segment
    // Valid slots form a prefix -> lane 0 is valid -> e is wave-uniform.
    int e = __builtin_amdgcn_readfirstlane(ent) >> 24;
    int row = ent & 0x00FFFFFF;
    int vrow = (ent >= 0) ? row : 0;              // invalid lanes: harmless work

    const float* __restrict__ w1 = W1 + e * (DIM * HID);
    const float4* __restrict__ xr = (const float4*)(x + (size_t)vrow * DIM);

    float h[HID];
#pragma unroll
    for (int j = 0; j < HID; j++) h[j] = b1[e * HID + j];

    // Prologue: first batch of 4 float4 loads in flight.
    float4 v0 = xr[0], v1 = xr[1], v2 = xr[2], v3 = xr[3];

#pragma unroll
    for (int b = 0; b < 8; b++) {
        float4 n0, n1, n2, n3;
        if (b < 7) {                               // issue next batch first
            n0 = xr[b * 4 + 4];
            n1 = xr[b * 4 + 5];
            n2 = xr[b * 4 + 6];
            n3 = xr[b * 4 + 7];
        }
        const int k0 = b * 16;                     // 16 features per batch
        const float xv[16] = {v0.x, v0.y, v0.z, v0.w, v1.x, v1.y, v1.z, v1.w,
                              v2.x, v2.y, v2.z, v2.w, v3.x, v3.y, v3.z, v3.w};
#pragma unroll
        for (int t = 0; t < 16; t++) {
#pragma unroll
            for (int j = 0; j < HID; j++)
                h[j] = fmaf(xv[t], w1[(k0 + t) * HID + j], h[j]);
        }
        if (b < 7) { v0 = n0; v1 = n1; v2 = n2; v3 = n3; }
    }

    float acc = b2[e];
#pragma unroll
    for (int j = 0; j < HID; j++) acc = fmaf(fmaxf(h[j], 0.0f), W2[e * HID + j], acc);
    if (ent >= 0) out[row] = fmaxf(acc, 0.0f);
}

// ---------------------------------------------------------------------------
// Fallback (only if ws_size is too small for the buckets): thread-per-row.
// ---------------------------------------------------------------------------
__global__ __launch_bounds__(256) void k_naive(const float* __restrict__ x,
                                               const int* __restrict__ sid,
                                               const float* __restrict__ W1,
                                               const float* __restrict__ b1,
                                               const float* __restrict__ W2,
                                               const float* __restrict__ b2,
                                               float* __restrict__ out) {
    int row = blockIdx.x * 256 + threadIdx.x;
    if (row >= N_ROWS) return;
    int e = sid[row];
    const float* w1 = W1 + e * (DIM * HID);
    const float* xr = x + (size_t)row * DIM;
    float h[HID];
#pragma unroll
    for (int j = 0; j < HID; j++) h[j] = b1[e * HID + j];
    for (int k = 0; k < DIM; k++) {
        float xk = xr[k];
#pragma unroll
        for (int j = 0; j < HID; j++) h[j] = fmaf(xk, w1[k * HID + j], h[j]);
    }
    float acc = b2[e];
#pragma unroll
    for (int j = 0; j < HID; j++) acc = fmaf(fmaxf(h[j], 0.0f), W2[e * HID + j], acc);
    out[row] = fmaxf(acc, 0.0f);
}

extern "C" void kernel_launch(void* const* d_in, const int* in_sizes, int n_in,
                              void* d_out, int out_size, void* d_ws, size_t ws_size,
                              hipStream_t stream) {
    const float* x   = (const float*)d_in[0];
    const int*   sid = (const int*)d_in[1];
    const float* W1  = (const float*)d_in[2];
    const float* b1  = (const float*)d_in[3];
    const float* W2  = (const float*)d_in[4];
    const float* b2  = (const float*)d_in[5];
    float* out = (float*)d_out;

    // Workspace layout: buckets | counts(32) | blockBase(NBLK1*NEXP)
    const size_t bucketBytes = (size_t)NSEG * 64 * sizeof(int);
    const size_t countBytes  = 32 * sizeof(int);
    const size_t bbBytes     = (size_t)NBLK1 * NEXP * sizeof(int);
    const size_t need = bucketBytes + countBytes + bbBytes;

    if (ws_size < need) {
        k_naive<<<(N_ROWS + 255) / 256, 256, 0, stream>>>(x, sid, W1, b1, W2, b2, out);
        return;
    }

    char* ws = (char*)d_ws;
    int* buckets   = (int*)ws;
    int* counts    = (int*)(ws + bucketBytes);
    int* blockBase = (int*)(ws + bucketBytes + countBytes);

    hipMemsetAsync(buckets, 0xFF, bucketBytes, stream);   // all -1
    hipMemsetAsync(counts, 0, countBytes, stream);
    k_hist<<<NBLK1, 256, 0, stream>>>(sid, counts, blockBase);
    k_scatter<<<NBLK1, 256, 0, stream>>>(sid, counts, blockBase, buckets);
    k_main<<<(NSEG + 3) / 4, 256, 0, stream>>>(x, W1, b1, W2, b2, buckets, out);
}

// Round 3
// 227.823 us; speedup vs baseline: 1.2232x; 1.0363x over previous
//
#include <hip/hip_runtime.h>

// Problem constants (fixed by the reference):
#define N_ROWS 262144
#define DIM    128
#define HID    16
#define NEXP   21
// Segments of 64 rows, each expert's region padded up to a multiple of 64.
#define NSEG   (N_ROWS / 64 + NEXP)   // 4096 + 21 = 4117 worst case
#define NBLK1  256                    // blocks for hist/scatter
#define RPB    (N_ROWS / NBLK1)       // 1024 rows per block
#define RPT    (RPB / 256)            // 4 rows per thread

// ---------------------------------------------------------------------------
// K1: per-block histogram of sid + reserve per-(block,expert) ranges.
// ---------------------------------------------------------------------------
__global__ __launch_bounds__(256) void k_hist(const int* __restrict__ sid,
                                              int* __restrict__ counts,
                                              int* __restrict__ blockBase) {
    __shared__ int lh[NEXP];
    int t = threadIdx.x;
    if (t < NEXP) lh[t] = 0;
    __syncthreads();
    int base = blockIdx.x * RPB + t;
#pragma unroll
    for (int r = 0; r < RPT; r++) {
        atomicAdd(&lh[sid[base + r * 256]], 1);
    }
    __syncthreads();
    if (t < NEXP) blockBase[blockIdx.x * NEXP + t] = atomicAdd(&counts[t], lh[t]);
}

// ---------------------------------------------------------------------------
// K2: scatter rows into per-expert 64-padded buckets.  Entry = row | (e<<24).
// Tail slots stay -1 (memset 0xFF).
// ---------------------------------------------------------------------------
__global__ __launch_bounds__(256) void k_scatter(const int* __restrict__ sid,
                                                 const int* __restrict__ counts,
                                                 const int* __restrict__ blockBase,
                                                 int* __restrict__ buckets) {
    __shared__ int sbase[NEXP];
    __shared__ int lcur[NEXP];
    int t = threadIdx.x;
    if (t == 0) {
        int acc = 0;
        for (int e = 0; e < NEXP; e++) {
            sbase[e] = acc + blockBase[blockIdx.x * NEXP + e];
            acc += ((counts[e] + 63) >> 6) << 6;   // pad each expert to 64
        }
    }
    if (t < NEXP) lcur[t] = 0;
    __syncthreads();
    int base = blockIdx.x * RPB + t;
#pragma unroll
    for (int r = 0; r < RPT; r++) {
        int row = base + r * 256;
        int e = sid[row];
        int lp = atomicAdd(&lcur[e], 1);
        buckets[sbase[e] + lp] = row | (e << 24);
    }
}

// ---------------------------------------------------------------------------
// K3: one wave per 64-row same-expert segment; expert is wave-uniform ->
// W1/b1/W2/b2 are scalar loads.  All 8 row float4 loads are issued up front
// and PINNED above a sched_barrier(0): rounds 1-2 proved the scheduler
// otherwise sinks each load to its use (VGPR_Count 20/32 -> depth ~1 ->
// 1.7 TB/s latency-limited).  Progressive vmcnt drain overlaps FMAs with the
// remaining in-flight loads.  // VGPR budget: 32 (x) + 16 (h) + ~12 misc.
// ---------------------------------------------------------------------------
#define FMA4(VV, KK)                                                         \
    _Pragma("unroll") for (int j = 0; j < HID; j++)                          \
        h[j] = fmaf(VV.x, w1[(KK + 0) * HID + j], h[j]);                     \
    _Pragma("unroll") for (int j = 0; j < HID; j++)                          \
        h[j] = fmaf(VV.y, w1[(KK + 1) * HID + j], h[j]);                     \
    _Pragma("unroll") for (int j = 0; j < HID; j++)                          \
        h[j] = fmaf(VV.z, w1[(KK + 2) * HID + j], h[j]);                     \
    _Pragma("unroll") for (int j = 0; j < HID; j++)                          \
        h[j] = fmaf(VV.w, w1[(KK + 3) * HID + j], h[j]);

__global__ __launch_bounds__(256, 4) void k_main(const float* __restrict__ x,
                                                 const float* __restrict__ W1,
                                                 const float* __restrict__ b1,
                                                 const float* __restrict__ W2,
                                                 const float* __restrict__ b2,
                                                 const int* __restrict__ buckets,
                                                 float* __restrict__ out) {
    int seg = blockIdx.x * 4 + (threadIdx.x >> 6);
    if (seg >= NSEG) return;
    int lane = threadIdx.x & 63;
    int ent = buckets[seg * 64 + lane];
    if (__ballot(ent >= 0) == 0ULL) return;       // wholly-empty tail segment
    // Valid slots form a prefix -> lane 0 is valid -> e is wave-uniform.
    int e = __builtin_amdgcn_readfirstlane(ent) >> 24;
    int row = ent & 0x00FFFFFF;
    int vrow = (ent >= 0) ? row : 0;              // invalid lanes: harmless work

    const float* __restrict__ w1 = W1 + e * (DIM * HID);
    const float4* __restrict__ xr = (const float4*)(x + (size_t)vrow * DIM);

    // ---- issue the ENTIRE row (8 x float4 = 512 B) before any compute ----
    float4 v0 = xr[0];
    float4 v1 = xr[1];
    float4 v2 = xr[2];
    float4 v3 = xr[3];
    float4 v4 = xr[4];
    float4 v5 = xr[5];
    float4 v6 = xr[6];
    float4 v7 = xr[7];
    __builtin_amdgcn_sched_barrier(0);   // nothing moves across: depth-8 MLP

    float h[HID];
#pragma unroll
    for (int j = 0; j < HID; j++) h[j] = b1[e * HID + j];

    FMA4(v0, 0)
    FMA4(v1, 4)
    FMA4(v2, 8)
    FMA4(v3, 12)
    FMA4(v4, 16)
    FMA4(v5, 20)
    FMA4(v6, 24)
    FMA4(v7, 28)
    // remaining 96 features:
    FMA4(v0, 0)  // placeholder never reached -- see note below
}

// NOTE: the macro expansion above covers k = 0..31 only if each FMA4 handles
// 4 features; with 8 vectors that is 32 features.  DIM=128 needs 32 vectors.
// The real kernel below loads 8 float4 (32 floats) per PASS and does 4 passes,
// pinning each pass's loads with sched_barrier.  (k_main above is unused.)

__global__ __launch_bounds__(256, 4) void k_main2(const float* __restrict__ x,
                                                  const float* __restrict__ W1,
                                                  const float* __restrict__ b1,
                                                  const float* __restrict__ W2,
                                                  const float* __restrict__ b2,
                                                  const int* __restrict__ buckets,
                                                  float* __restrict__ out) {
    int seg = blockIdx.x * 4 + (threadIdx.x >> 6);
    if (seg >= NSEG) return;
    int lane = threadIdx.x & 63;
    int ent = buckets[seg * 64 + lane];
    if (__ballot(ent >= 0) == 0ULL) return;
    int e = __builtin_amdgcn_readfirstlane(ent) >> 24;
    int row = ent & 0x00FFFFFF;
    int vrow = (ent >= 0) ? row : 0;

    const float* __restrict__ w1 = W1 + e * (DIM * HID);
    const float4* __restrict__ xr = (const float4*)(x + (size_t)vrow * DIM);

    // Issue ALL 32 float4 loads?  That is 128 VGPRs of x alone -- too much.
    // Instead: two half-row batches of 4 float4 (64 B) each, ping-pong, with
    // sched_barrier pinning each batch issue point.  Depth 4-8 sustained.
    float4 a0 = xr[0], a1 = xr[1], a2 = xr[2], a3 = xr[3];
    float4 b0 = xr[4], b1v = xr[5], b2v = xr[6], b3 = xr[7];
    __builtin_amdgcn_sched_barrier(0);

    float h[HID];
#pragma unroll
    for (int j = 0; j < HID; j++) h[j] = b1[e * HID + j];

#pragma unroll
    for (int half = 0; half < 4; half++) {
        // compute on batch A (features half*32 .. half*32+15)
        const int k0 = half * 32;
        FMA4(a0, k0 + 0)
        FMA4(a1, k0 + 4)
        FMA4(a2, k0 + 8)
        FMA4(a3, k0 + 12)
        // refill batch A with the NEXT half's first 4 vectors while B computes
        if (half < 3) {
            a0 = xr[(half + 1) * 8 + 0];
            a1 = xr[(half + 1) * 8 + 1];
            a2 = xr[(half + 1) * 8 + 2];
            a3 = xr[(half + 1) * 8 + 3];
            __builtin_amdgcn_sched_barrier(0);
        }
        FMA4(b0, k0 + 16)
        FMA4(b1v, k0 + 20)
        FMA4(b2v, k0 + 24)
        FMA4(b3, k0 + 28)
        if (half < 3) {
            b0 = xr[(half + 1) * 8 + 4];
            b1v = xr[(half + 1) * 8 + 5];
            b2v = xr[(half + 1) * 8 + 6];
            b3 = xr[(half + 1) * 8 + 7];
            __builtin_amdgcn_sched_barrier(0);
        }
    }

    float acc = b2[e];
#pragma unroll
    for (int j = 0; j < HID; j++) acc = fmaf(fmaxf(h[j], 0.0f), W2[e * HID + j], acc);
    if (ent >= 0) out[row] = fmaxf(acc, 0.0f);
}

// ---------------------------------------------------------------------------
// Fallback (only if ws_size is too small for the buckets): thread-per-row.
// ---------------------------------------------------------------------------
__global__ __launch_bounds__(256) void k_naive(const float* __restrict__ x,
                                               const int* __restrict__ sid,
                                               const float* __restrict__ W1,
                                               const float* __restrict__ b1,
                                               const float* __restrict__ W2,
                                               const float* __restrict__ b2,
                                               float* __restrict__ out) {
    int row = blockIdx.x * 256 + threadIdx.x;
    if (row >= N_ROWS) return;
    int e = sid[row];
    const float* w1 = W1 + e * (DIM * HID);
    const float* xr = x + (size_t)row * DIM;
    float h[HID];
#pragma unroll
    for (int j = 0; j < HID; j++) h[j] = b1[e * HID + j];
    for (int k = 0; k < DIM; k++) {
        float xk = xr[k];
#pragma unroll
        for (int j = 0; j < HID; j++) h[j] = fmaf(xk, w1[k * HID + j], h[j]);
    }
    float acc = b2[e];
#pragma unroll
    for (int j = 0; j < HID; j++) acc = fmaf(fmaxf(h[j], 0.0f), W2[e * HID + j], acc);
    out[row] = fmaxf(acc, 0.0f);
}

extern "C" void kernel_launch(void* const* d_in, const int* in_sizes, int n_in,
                              void* d_out, int out_size, void* d_ws, size_t ws_size,
                              hipStream_t stream) {
    const float* x   = (const float*)d_in[0];
    const int*   sid = (const int*)d_in[1];
    const float* W1  = (const float*)d_in[2];
    const float* b1  = (const float*)d_in[3];
    const float* W2  = (const float*)d_in[4];
    const float* b2  = (const float*)d_in[5];
    float* out = (float*)d_out;

    // Workspace layout: buckets | counts(32) | blockBase(NBLK1*NEXP)
    const size_t bucketBytes = (size_t)NSEG * 64 * sizeof(int);
    const size_t countBytes  = 32 * sizeof(int);
    const size_t bbBytes     = (size_t)NBLK1 * NEXP * sizeof(int);
    const size_t need = bucketBytes + countBytes + bbBytes;

    if (ws_size < need) {
        k_naive<<<(N_ROWS + 255) / 256, 256, 0, stream>>>(x, sid, W1, b1, W2, b2, out);
        return;
    }

    char* ws = (char*)d_ws;
    int* buckets   = (int*)ws;
    int* counts    = (int*)(ws + bucketBytes);
    int* blockBase = (int*)(ws + bucketBytes + countBytes);

    hipMemsetAsync(buckets, 0xFF, bucketBytes, stream);   // all -1
    hipMemsetAsync(counts, 0, countBytes, stream);
    k_hist<<<NBLK1, 256, 0, stream>>>(sid, counts, blockBase);
    k_scatter<<<NBLK1, 256, 0, stream>>>(sid, counts, blockBase, buckets);
    k_main2<<<(NSEG + 3) / 4, 256, 0, stream>>>(x, W1, b1, W2, b2, buckets, out);
}